// Round 4
// baseline (485.585 us; speedup 1.0000x reference)
//
#include <hip/hip_runtime.h>
#include <hip/hip_bf16.h>

// MoE experts, E=8 H=1024 I=4096 T=8192, f32 I/O, bf16 MFMA compute.
// Reassociation: M_e = W1_e @ W2_e (68.7 GF), down = x @ M_e (17.2 GF).
// Round-4: raise occupancy to 4 blocks/CU in both GEMMs.
//   wgemm: split-K (KS=2, bf16 partials) -> grid 1024; reduce adds partials.
//   tgemm: 64x128 tiles -> grid 1024.
// Workspace (160 MB, proven in round 3), with aliasing:
//   [0,64)MB   w1b  (bf16 W1)      ... later reused as xb [0,16)MB
//   [64,128)MB w2t  (bf16 W2^T)
//   [128,144)  P0   (bf16 partial) ... later overwritten by mt
//   [144,160)  P1   (bf16 partial)

typedef unsigned short u16;
typedef unsigned int u32;
typedef __attribute__((ext_vector_type(8))) short bf16x8;   // 8 bf16 = 4 VGPR
typedef __attribute__((ext_vector_type(4))) float f32x4;
typedef __attribute__((ext_vector_type(4))) u32 u32x4;

#define E_N 8
#define H_N 1024
#define I_N 4096
#define T_N 8192

#define GLD2LDS16(g, l)                                                        \
  __builtin_amdgcn_global_load_lds(                                            \
      (const __attribute__((address_space(1))) void*)(g),                      \
      (__attribute__((address_space(3))) void*)(l), 16, 0, 0)

__device__ __forceinline__ u32 pkbf(float lo, float hi) {
  u32 a = __float_as_uint(lo) + 0x8000u;
  u32 b = __float_as_uint(hi) + 0x8000u;
  return __builtin_amdgcn_perm(b, a, 0x07060302u);
}

__device__ __forceinline__ u16 f2bf(float f) {
  __hip_bfloat16 h = __float2bfloat16(f);
  return *(reinterpret_cast<u16*>(&h));
}

__device__ __forceinline__ float bf2f(u16 v) {
  u32 x = (u32)v << 16;
  return __uint_as_float(x);
}

// ---------------------------------------------------------------------------
// f32 -> bf16, 16 elems/thread
// ---------------------------------------------------------------------------
__global__ __launch_bounds__(256) void cvt_kernel(const float* __restrict__ src,
                                                  u16* __restrict__ dst) {
  const size_t i = ((size_t)blockIdx.x * 256 + threadIdx.x) * 16;
  float4 a = *(const float4*)(src + i);
  float4 b = *(const float4*)(src + i + 4);
  float4 c = *(const float4*)(src + i + 8);
  float4 d = *(const float4*)(src + i + 12);
  *(u32x4*)(dst + i) = (u32x4){pkbf(a.x, a.y), pkbf(a.z, a.w),
                               pkbf(b.x, b.y), pkbf(b.z, b.w)};
  *(u32x4*)(dst + i + 8) = (u32x4){pkbf(c.x, c.y), pkbf(c.z, c.w),
                                   pkbf(d.x, d.y), pkbf(d.z, d.w)};
}

// ---------------------------------------------------------------------------
// W2 [E][I][H] f32 -> W2T [E][H][I] bf16. 64x64 tiles via LDS (pad 65).
// ---------------------------------------------------------------------------
__global__ __launch_bounds__(256) void transp_kernel(const float* __restrict__ w2,
                                                     u16* __restrict__ w2t) {
  __shared__ float tile[64 * 65];
  const int tid = threadIdx.x;
  const int h0 = blockIdx.x * 64;
  const int i0 = blockIdx.y * 64;
  const float* src = w2 + (size_t)blockIdx.z * I_N * H_N;
  u16* dst = w2t + (size_t)blockIdx.z * H_N * I_N;

  {
    const int r = tid >> 4;
    const int c4 = (tid & 15) * 4;
#pragma unroll
    for (int rr = 0; rr < 4; rr++) {
      const int row = rr * 16 + r;
      float4 v = *(const float4*)(src + (size_t)(i0 + row) * H_N + h0 + c4);
      tile[row * 65 + c4 + 0] = v.x;
      tile[row * 65 + c4 + 1] = v.y;
      tile[row * 65 + c4 + 2] = v.z;
      tile[row * 65 + c4 + 3] = v.w;
    }
  }
  __syncthreads();
  {
    const int hr = tid >> 3;
    const int ic = (tid & 7) * 8;
#pragma unroll
    for (int hh = 0; hh < 2; hh++) {
      const int h = hh * 32 + hr;
      u32 p[4];
#pragma unroll
      for (int j = 0; j < 4; j++)
        p[j] = pkbf(tile[(ic + 2 * j) * 65 + h], tile[(ic + 2 * j + 1) * 65 + h]);
      *(u32x4*)(dst + (size_t)(h0 + h) * I_N + i0 + ic) =
          (u32x4){p[0], p[1], p[2], p[3]};
    }
  }
}

// ---------------------------------------------------------------------------
// Weight GEMM, split-K: P[ks][e][h2][h1] = sum_{i in half ks} W2T[e][h2][i]*W1b[e][h1][i]
// grid 1024 = ks(2) x e(8) x row(8) x col(8). Tile 128x128, BK=32, 4 waves.
// ---------------------------------------------------------------------------
__global__ __launch_bounds__(256) void wgemm_kernel(const u16* __restrict__ w2t,
                                                    const u16* __restrict__ w1b,
                                                    u16* __restrict__ P) {
  __shared__ u16 ldsA[4096];  // [m:128][k:32]
  __shared__ u16 ldsB[4096];  // [n:128][k:32]

  const int tid = threadIdx.x;
  const int lane = tid & 63;
  const int wv = tid >> 6;
  const int wm = wv >> 1, wn = wv & 1;
  const int lm = lane & 15, quad = lane >> 4;

  const int blk = blockIdx.x;
  const int ks = blk >> 9;
  const int e = (blk >> 6) & 7;
  const int t = blk & 63;
  const int row0 = (t >> 3) * 128;  // h2
  const int col0 = (t & 7) * 128;   // h1
  const int kbase = ks * 2048;

  const u16* Ae = w2t + (size_t)e * H_N * I_N;
  const u16* Be = w1b + (size_t)e * H_N * I_N;
  u16* Pe = P + (size_t)ks * E_N * H_N * H_N + (size_t)e * H_N * H_N;

  const int s_r = tid >> 2;
  const int s_k = (tid & 3) * 8;
  const u16* gA0 = Ae + (size_t)(row0 + s_r) * I_N + kbase + s_k;
  const u16* gA1 = gA0 + (size_t)64 * I_N;
  const u16* gB0 = Be + (size_t)(col0 + s_r) * I_N + kbase + s_k;
  const u16* gB1 = gB0 + (size_t)64 * I_N;
  u16* ldsA_dst = ldsA + wv * 512;
  u16* ldsB_dst = ldsB + wv * 512;

  f32x4 acc[4][4];
#pragma unroll
  for (int i = 0; i < 4; i++)
#pragma unroll
    for (int j = 0; j < 4; j++) acc[i][j] = (f32x4){0.f, 0.f, 0.f, 0.f};

  for (int k0 = 0; k0 < 2048; k0 += 32) {
    GLD2LDS16(gA0 + k0, ldsA_dst);
    GLD2LDS16(gA1 + k0, ldsA_dst + 2048);
    GLD2LDS16(gB0 + k0, ldsB_dst);
    GLD2LDS16(gB1 + k0, ldsB_dst + 2048);

    __syncthreads();

    bf16x8 af[4], bfr[4];
#pragma unroll
    for (int mi = 0; mi < 4; mi++)
      af[mi] = *(const bf16x8*)(ldsA + (wm * 64 + mi * 16 + lm) * 32 + quad * 8);
#pragma unroll
    for (int ni = 0; ni < 4; ni++)
      bfr[ni] = *(const bf16x8*)(ldsB + (wn * 64 + ni * 16 + lm) * 32 + quad * 8);
#pragma unroll
    for (int mi = 0; mi < 4; mi++)
#pragma unroll
      for (int ni = 0; ni < 4; ni++)
        acc[mi][ni] = __builtin_amdgcn_mfma_f32_16x16x32_bf16(
            af[mi], bfr[ni], acc[mi][ni], 0, 0, 0);

    __syncthreads();
  }

  const int orow = row0 + wm * 64 + quad * 4;
  const int ocol = col0 + wn * 64 + lm;
#pragma unroll
  for (int mi = 0; mi < 4; mi++)
#pragma unroll
    for (int ni = 0; ni < 4; ni++)
#pragma unroll
      for (int r = 0; r < 4; r++)
        Pe[(size_t)(orow + mi * 16 + r) * H_N + ocol + ni * 16] =
            f2bf(acc[mi][ni][r]);
}

// ---------------------------------------------------------------------------
// reduce: mt[i] = bf16(P0[i] + P1[i]); mt aliases P0 (same-index RMW, safe)
// 8 elems/thread, 4096 blocks
// ---------------------------------------------------------------------------
__global__ __launch_bounds__(256) void reduce_kernel(const u16* __restrict__ P0,
                                                     const u16* __restrict__ P1,
                                                     u16* __restrict__ mt) {
  const size_t i = ((size_t)blockIdx.x * 256 + threadIdx.x) * 8;
  u32x4 a = *(const u32x4*)(P0 + i);
  u32x4 b = *(const u32x4*)(P1 + i);
  u32 o[4];
#pragma unroll
  for (int j = 0; j < 4; j++) {
    float lo = bf2f((u16)(a[j] & 0xffffu)) + bf2f((u16)(b[j] & 0xffffu));
    float hi = bf2f((u16)(a[j] >> 16)) + bf2f((u16)(b[j] >> 16));
    o[j] = pkbf(lo, hi);
  }
  *(u32x4*)(mt + i) = (u32x4){o[0], o[1], o[2], o[3]};
}

// ---------------------------------------------------------------------------
// Token GEMM: out[t][h2] = sum_h1 xb[t][h1] * Mt[e(t)][h2][h1]
// Tile 64(m) x 128(n), BK=32, 4 waves each 64x32. grid 1024 = 128 m x 8 n.
// ---------------------------------------------------------------------------
__global__ __launch_bounds__(256) void tgemm_kernel(const u16* __restrict__ xb,
                                                    const int* __restrict__ bsz,
                                                    const u16* __restrict__ mt,
                                                    float* __restrict__ out) {
  __shared__ u16 ldsA[2048];  // x tile  [m:64][k:32]
  __shared__ u16 ldsB[4096];  // Mt tile [n:128][k:32]

  const int tid = threadIdx.x;
  const int lane = tid & 63;
  const int wv = tid >> 6;
  const int lm = lane & 15, quad = lane >> 4;

  const int bm = blockIdx.x >> 3, bn = blockIdx.x & 7;
  const int row0 = bm * 64;   // token
  const int col0 = bn * 128;  // h2

  int e = 0, start = 0;
#pragma unroll
  for (int i = 0; i < E_N; i++) {
    int b = bsz[i];
    if (row0 >= start + b) { start += b; e = i + 1; }
  }
  const u16* mte = mt + (size_t)e * H_N * H_N;

  // staging: per wave, A rows [wv*16, wv*16+16), B rows [wv*32, wv*32+32)
  const int l_r = lane >> 2;       // 0..15
  const int l_k = (lane & 3) * 8;  // 0..24
  const u16* gA = xb + (size_t)(row0 + wv * 16 + l_r) * H_N + l_k;
  const u16* gB0 = mte + (size_t)(col0 + wv * 32 + l_r) * H_N + l_k;
  const u16* gB1 = gB0 + (size_t)16 * H_N;
  u16* ldsA_dst = ldsA + wv * 512;   // 16 rows * 32k
  u16* ldsB_dst = ldsB + wv * 1024;  // 32 rows * 32k

  f32x4 acc[4][2];
#pragma unroll
  for (int i = 0; i < 4; i++)
#pragma unroll
    for (int j = 0; j < 2; j++) acc[i][j] = (f32x4){0.f, 0.f, 0.f, 0.f};

  for (int k0 = 0; k0 < H_N; k0 += 32) {
    GLD2LDS16(gA + k0, ldsA_dst);
    GLD2LDS16(gB0 + k0, ldsB_dst);
    GLD2LDS16(gB1 + k0, ldsB_dst + 512);

    __syncthreads();

    bf16x8 af[4], bfr[2];
#pragma unroll
    for (int mi = 0; mi < 4; mi++)
      af[mi] = *(const bf16x8*)(ldsA + (mi * 16 + lm) * 32 + quad * 8);
#pragma unroll
    for (int ni = 0; ni < 2; ni++)
      bfr[ni] = *(const bf16x8*)(ldsB + (wv * 32 + ni * 16 + lm) * 32 + quad * 8);
#pragma unroll
    for (int mi = 0; mi < 4; mi++)
#pragma unroll
      for (int ni = 0; ni < 2; ni++)
        acc[mi][ni] = __builtin_amdgcn_mfma_f32_16x16x32_bf16(
            af[mi], bfr[ni], acc[mi][ni], 0, 0, 0);

    __syncthreads();
  }

  const int orow = row0 + quad * 4;
  const int ocol = col0 + wv * 32 + lm;
#pragma unroll
  for (int mi = 0; mi < 4; mi++)
#pragma unroll
    for (int ni = 0; ni < 2; ni++)
#pragma unroll
      for (int r = 0; r < 4; r++)
        out[(size_t)(orow + mi * 16 + r) * H_N + ocol + ni * 16] =
            acc[mi][ni][r];
}

extern "C" void kernel_launch(void* const* d_in, const int* in_sizes, int n_in,
                              void* d_out, int out_size, void* d_ws,
                              size_t ws_size, hipStream_t stream) {
  (void)in_sizes; (void)n_in; (void)out_size; (void)ws_size;
  const float* hiddens = (const float*)d_in[0];
  const int* bsz = (const int*)d_in[1];
  const float* w1 = (const float*)d_in[2];
  const float* w2 = (const float*)d_in[3];
  float* out = (float*)d_out;

  char* ws = (char*)d_ws;
  u16* w1b = (u16*)(ws);                                  // [0,64) MB
  u16* w2t = (u16*)(ws + (size_t)64 * 1024 * 1024);       // [64,128)
  u16* P   = (u16*)(ws + (size_t)128 * 1024 * 1024);      // [128,160): P0,P1
  u16* P1  = (u16*)(ws + (size_t)144 * 1024 * 1024);
  u16* mt  = (u16*)(ws + (size_t)128 * 1024 * 1024);      // aliases P0
  u16* xb  = (u16*)(ws);                                  // aliases dead w1b

  cvt_kernel<<<dim3(8192), 256, 0, stream>>>(w1, w1b);         // 33.5M elems
  transp_kernel<<<dim3(16, 64, E_N), 256, 0, stream>>>(w2, w2t);

  wgemm_kernel<<<dim3(1024), 256, 0, stream>>>(w2t, w1b, P);   // split-K
  reduce_kernel<<<dim3(4096), 256, 0, stream>>>(P, P1, mt);

  cvt_kernel<<<dim3(2048), 256, 0, stream>>>(hiddens, xb);     // x: 8.4M elems
  tgemm_kernel<<<dim3(1024), 256, 0, stream>>>(xb, bsz, mt, out);
}